// Round 3
// baseline (775.553 us; speedup 1.0000x reference)
//
#include <hip/hip_runtime.h>
#include <hip/hip_bf16.h>

// SlowLSTM on MI355X (gfx950). B=4096, D=H=2048.
// Round 6 (resubmit of round 5; infra failed rounds 0-2, kernel unmeasured):
// kernel 2 staging via __builtin_amdgcn_global_load_lds width=16 (m97 ladder
// step 3: 517->874 TF on this 128x128/BK=32/2-barrier structure), bijective
// XCD-aware blockIdx swizzle (grid 2048 % 8 == 0). K-loop split into X-phase
// then H-phase (hoists base addr to SGPRs; removes per-iter select).
// F32-input variant keeps register staging for A (needs f2b); B path (WT,
// always bf16) uses DMA in both. Kernel 1 (weight transpose) unchanged.

typedef unsigned short u16;
typedef __attribute__((ext_vector_type(4))) unsigned short u16x4;
typedef __attribute__((ext_vector_type(8))) unsigned short u16x8;
typedef __attribute__((ext_vector_type(8))) __bf16 bf16x8;
typedef __attribute__((ext_vector_type(4))) float f32x4;

#define BH_TOTAL (4096 * 2048)

__device__ __forceinline__ float b2f(u16 u) {
  union { unsigned int i; float f; } v; v.i = ((unsigned int)u) << 16; return v.f;
}
__device__ __forceinline__ u16 f2b(float f) {
  union { float f; unsigned int i; } v; v.f = f;
  unsigned int r = v.i + 0x7fffu + ((v.i >> 16) & 1u);  // RNE
  return (u16)(r >> 16);
}
__device__ __forceinline__ float sigmoidf_(float x) {
  return 1.0f / (1.0f + __expf(-x));
}

// Async global->LDS, 16 bytes per lane. LDS dest must be linear in lane order
// (wave-uniform base + lane*16) -- our c = t + i*256 mapping satisfies this.
__device__ __forceinline__ void gload_lds16(const void* g, void* l) {
  __builtin_amdgcn_global_load_lds(
      (const __attribute__((address_space(1))) unsigned int*)g,
      (__attribute__((address_space(3))) unsigned int*)l, 16, 0, 0);
}

// fp32 read as u16 shows mantissa halves with huge "bf16 exponents";
// N(0,1)-scale bf16 never has exponent >= 0x90 (|v| >= 2^17).
__device__ __forceinline__ bool input_is_f32(const u16* Xu) {
  const int lane = threadIdx.x & 63;
  unsigned bad = 0;
#pragma unroll
  for (int j = 0; j < 4; ++j) {
    unsigned u = Xu[lane + (j << 6)];
    bad |= (((u >> 7) & 0xFFu) >= 0x90u) ? 1u : 0u;
  }
  return __any((int)bad) != 0;
}

// ---------------- Kernel 1: weight transpose -> WT[g][n][kcat] (bf16) ----
// grid 8192 x 256. m8 = bid>>10 = 2*g + phase (0=x,1=h). 64x64 tiles.
template <bool F32>
__global__ __launch_bounds__(256) void wt_transpose_kernel(
    const void* __restrict__ w0, const void* __restrict__ w1,
    const void* __restrict__ w2, const void* __restrict__ w3,
    const void* __restrict__ w4, const void* __restrict__ w5,
    const void* __restrict__ w6, const void* __restrict__ w7,
    u16* __restrict__ WT, const u16* __restrict__ Xu) {
  if (input_is_f32(Xu) != F32) return;
  __shared__ u16 tile[64][65];
  const int bid = blockIdx.x;
  const int m8 = bid >> 10;
  const void* srcs[8] = {w0, w1, w2, w3, w4, w5, w6, w7};
  const int g = m8 >> 1, ph = m8 & 1;
  const int tt = bid & 1023;
  const int k0 = (tt >> 5) << 6;
  const int n0 = (tt & 31) << 6;
  const int t = threadIdx.x;

#pragma unroll
  for (int i = 0; i < 4; ++i) {
    const int q = t + (i << 8);
    const int row = q >> 4;        // k within tile
    const int cx = (q & 15) << 2;  // n within tile (4 elems)
    if (F32) {
      const float* src = (const float*)srcs[m8];
      f32x4 v = *(const f32x4*)(src + (size_t)(k0 + row) * 2048 + n0 + cx);
      tile[row][cx + 0] = f2b(v[0]);
      tile[row][cx + 1] = f2b(v[1]);
      tile[row][cx + 2] = f2b(v[2]);
      tile[row][cx + 3] = f2b(v[3]);
    } else {
      const u16* src = (const u16*)srcs[m8];
      u16x4 v = *(const u16x4*)(src + (size_t)(k0 + row) * 2048 + n0 + cx);
      tile[row][cx + 0] = v[0];
      tile[row][cx + 1] = v[1];
      tile[row][cx + 2] = v[2];
      tile[row][cx + 3] = v[3];
    }
  }
  __syncthreads();
  const size_t gbase = ((size_t)g << 23) + (size_t)ph * 2048 + k0;
#pragma unroll
  for (int i = 0; i < 4; ++i) {
    const int q = t + (i << 8);
    const int nrow = q >> 4;       // n within tile
    const int kx = (q & 15) << 2;  // k within tile (4 elems)
    u16x4 v;
    v[0] = tile[kx + 0][nrow];
    v[1] = tile[kx + 1][nrow];
    v[2] = tile[kx + 2][nrow];
    v[3] = tile[kx + 3][nrow];
    *(u16x4*)(WT + gbase + (size_t)(n0 + nrow) * 4096 + kx) = v;
  }
}

// ---------------- Kernel 2: fused GEMM + LSTM (fp32 out) ----------------
// grid 2048 = 32 m-tiles x 64 n-tiles; 256 thr = 4 waves (2 m x 2 n halves).
// Staging: global_load_lds dwordx4 (A: bf16 path only; B: always).
template <bool F32>
__global__ __launch_bounds__(256) void lstm_gemm_kernel(
    const void* __restrict__ Xp, const void* __restrict__ Hp,
    const void* __restrict__ Cp, const u16* __restrict__ WT,
    const void* __restrict__ bip, const void* __restrict__ bfp,
    const void* __restrict__ bop, const void* __restrict__ bcp,
    float* __restrict__ Out) {
  if (input_is_f32((const u16*)Xp) != F32) return;
  __shared__ u16 As[128 * 32];     // [m][k]
  __shared__ u16 Bs[4 * 32 * 32];  // [gate][n][k]

  const int t = threadIdx.x;
  const int wave = t >> 6;
  const int lane = t & 63;
  const int ln = lane & 15;
  const int quad = lane >> 4;
  const int wm = wave >> 1;
  const int wn = wave & 1;
  // XCD-aware bijective swizzle: grid 2048, 8 XCDs -> 256-block chunks.
  const int b0 = blockIdx.x;
  const int bid = ((b0 & 7) << 8) + (b0 >> 3);
  const int m0 = (bid >> 6) << 7;
  const int n0 = (bid & 63) << 5;

  f32x4 acc[4][4];
#pragma unroll
  for (int g = 0; g < 4; ++g)
#pragma unroll
    for (int im = 0; im < 4; ++im) acc[g][im] = (f32x4)0.0f;

  // Two phases: X (kcat 0..2047) then H (kcat 2048..4095).
  for (int phse = 0; phse < 2; ++phse) {
    const void* Asrc = phse ? Hp : Xp;
    for (int kt = 0; kt < 64; ++kt) {
      const int kk = kt << 5;                  // k offset in source
      const int kcat = (phse << 11) + kk;      // k offset in WT rows
      if (!F32) {
        // A tile: 128 rows x 32 k (bf16) = 8 KiB -> 2 DMA issues/thread.
#pragma unroll
        for (int i = 0; i < 2; ++i) {
          const int c = t + (i << 8);
          const int row = m0 + (c >> 2);
          const int ko = kk + ((c & 3) << 3);
          gload_lds16((const u16*)Asrc + (size_t)row * 2048 + ko, As + c * 8);
        }
      } else {
#pragma unroll
        for (int i = 0; i < 2; ++i) {
          const int c = t + (i << 8);
          const int row = m0 + (c >> 2);
          const int ko = kk + ((c & 3) << 3);
          const float* p = (const float*)Asrc + (size_t)row * 2048 + ko;
          f32x4 v0 = *(const f32x4*)p;
          f32x4 v1 = *(const f32x4*)(p + 4);
          u16x8 w;
          w[0] = f2b(v0[0]); w[1] = f2b(v0[1]); w[2] = f2b(v0[2]); w[3] = f2b(v0[3]);
          w[4] = f2b(v1[0]); w[5] = f2b(v1[1]); w[6] = f2b(v1[2]); w[7] = f2b(v1[3]);
          *(u16x8*)(As + c * 8) = w;
        }
      }
      // B tile: 4 gates x 32 n x 32 k (bf16, from WT) = 8 KiB -> 2 DMA/thr.
#pragma unroll
      for (int i = 0; i < 2; ++i) {
        const int c = t + (i << 8);
        const int g = c >> 7;
        const int n = (c & 127) >> 2;
        const int kc = (c & 3) << 3;
        gload_lds16(WT + ((size_t)g << 23) + (size_t)(n0 + n) * 4096 + kcat + kc,
                    Bs + c * 8);
      }
      __syncthreads();

      bf16x8 a[4], b[4];
      const bf16x8* As8 = (const bf16x8*)As;
      const bf16x8* Bs8 = (const bf16x8*)Bs;
#pragma unroll
      for (int im = 0; im < 4; ++im)
        a[im] = As8[(wm * 64 + im * 16 + ln) * 4 + quad];
#pragma unroll
      for (int g = 0; g < 4; ++g)
        b[g] = Bs8[(g * 32 + wn * 16 + ln) * 4 + quad];
#pragma unroll
      for (int g = 0; g < 4; ++g)
#pragma unroll
        for (int im = 0; im < 4; ++im)
          acc[g][im] = __builtin_amdgcn_mfma_f32_16x16x32_bf16(
              a[im], b[g], acc[g][im], 0, 0, 0);
      __syncthreads();
    }
  }

  // Epilogue: bias + activations + elementwise; FP32 stores.
  const int ncol = n0 + wn * 16 + ln;
  float Bi, Bf, Bo, Bc;
  if (F32) {
    Bi = ((const float*)bip)[ncol]; Bf = ((const float*)bfp)[ncol];
    Bo = ((const float*)bop)[ncol]; Bc = ((const float*)bcp)[ncol];
  } else {
    Bi = b2f(((const u16*)bip)[ncol]); Bf = b2f(((const u16*)bfp)[ncol]);
    Bo = b2f(((const u16*)bop)[ncol]); Bc = b2f(((const u16*)bcp)[ncol]);
  }
#pragma unroll
  for (int im = 0; im < 4; ++im) {
#pragma unroll
    for (int r = 0; r < 4; ++r) {
      const int m = m0 + wm * 64 + im * 16 + quad * 4 + r;
      const size_t idx = (size_t)m * 2048 + ncol;
      const float gi = sigmoidf_(acc[0][im][r] + Bi);
      const float gf = sigmoidf_(acc[1][im][r] + Bf);
      const float go = sigmoidf_(acc[2][im][r] + Bo);
      const float gc = tanhf(acc[3][im][r] + Bc);
      const float c_in = F32 ? ((const float*)Cp)[idx] : b2f(((const u16*)Cp)[idx]);
      const float ct = gf * c_in + gi * gc;
      const float ht = go * tanhf(ct);
      Out[idx] = ht;             // h_t (fp32)
      Out[idx + BH_TOTAL] = ct;  // c_t (fp32)
    }
  }
}

extern "C" void kernel_launch(void* const* d_in, const int* in_sizes, int n_in,
                              void* d_out, int out_size, void* d_ws,
                              size_t ws_size, hipStream_t stream) {
  const u16* Xu = (const u16*)d_in[0];
  u16* WT = (u16*)d_ws;  // 64 MiB

  hipLaunchKernelGGL((wt_transpose_kernel<false>), dim3(8192), dim3(256), 0,
                     stream, d_in[3], d_in[4], d_in[5], d_in[6], d_in[7],
                     d_in[8], d_in[9], d_in[10], WT, Xu);
  hipLaunchKernelGGL((wt_transpose_kernel<true>), dim3(8192), dim3(256), 0,
                     stream, d_in[3], d_in[4], d_in[5], d_in[6], d_in[7],
                     d_in[8], d_in[9], d_in[10], WT, Xu);
  hipLaunchKernelGGL((lstm_gemm_kernel<false>), dim3(2048), dim3(256), 0,
                     stream, d_in[0], d_in[1], d_in[2], WT, d_in[11], d_in[12],
                     d_in[13], d_in[14], (float*)d_out);
  hipLaunchKernelGGL((lstm_gemm_kernel<true>), dim3(2048), dim3(256), 0,
                     stream, d_in[0], d_in[1], d_in[2], WT, d_in[11], d_in[12],
                     d_in[13], d_in[14], (float*)d_out);
}

// Round 6
// 694.963 us; speedup vs baseline: 1.1160x; 1.1160x over previous
//
#include <hip/hip_runtime.h>
#include <hip/hip_bf16.h>

// SlowLSTM on MI355X (gfx950). B=4096, D=H=2048.
// Round 9 (3rd resubmit of the 2-phase pipeline; infra failed rounds 4-5
// before dispatch — kernel still unmeasured).
// Round-6 measured 574us gemm, MfmaUtil 20.5 / VALU 33 / HBM 26% / LDS 21%
// => latency-bound on per-kt vmcnt(0) drain (stage->drain->compute serial).
// Fix: T3/T4 minimum 2-phase pipeline — double-buffered LDS (32 KB), issue
// next tile's global_load_lds BEFORE computing current, ONE barrier per kt.
// Unrolled x2 so buffer idx is compile-time. Fast tanh epilogue.
// Kernel 1 (weight transpose -> WT[g][n][kcat] bf16, 64 MiB ws) unchanged.

typedef unsigned short u16;
typedef __attribute__((ext_vector_type(4))) unsigned short u16x4;
typedef __attribute__((ext_vector_type(8))) unsigned short u16x8;
typedef __attribute__((ext_vector_type(8))) __bf16 bf16x8;
typedef __attribute__((ext_vector_type(4))) float f32x4;

#define BH_TOTAL (4096 * 2048)

__device__ __forceinline__ float b2f(u16 u) {
  union { unsigned int i; float f; } v; v.i = ((unsigned int)u) << 16; return v.f;
}
__device__ __forceinline__ u16 f2b(float f) {
  union { float f; unsigned int i; } v; v.f = f;
  unsigned int r = v.i + 0x7fffu + ((v.i >> 16) & 1u);  // RNE
  return (u16)(r >> 16);
}
__device__ __forceinline__ float sigmoidf_(float x) {
  return 1.0f / (1.0f + __expf(-x));
}
// tanh(x) = 1 - 2/(e^{2x}+1); exact at +-inf via __expf saturation.
__device__ __forceinline__ float tanh_fast(float x) {
  float e = __expf(2.0f * x);
  return 1.0f - 2.0f / (e + 1.0f);
}

// Async global->LDS, 16 bytes per lane. LDS dest must be linear in lane order
// (wave-uniform base + lane*16) -- our t*8 u16 mapping satisfies this.
__device__ __forceinline__ void gload_lds16(const u16* g, u16* l) {
  __builtin_amdgcn_global_load_lds(
      (const __attribute__((address_space(1))) unsigned int*)g,
      (__attribute__((address_space(3))) unsigned int*)l, 16, 0, 0);
}

// fp32 read as u16 shows mantissa halves with huge "bf16 exponents";
// N(0,1)-scale bf16 never has exponent >= 0x90 (|v| >= 2^17).
__device__ __forceinline__ bool input_is_f32(const u16* Xu) {
  const int lane = threadIdx.x & 63;
  unsigned bad = 0;
#pragma unroll
  for (int j = 0; j < 4; ++j) {
    unsigned u = Xu[lane + (j << 6)];
    bad |= (((u >> 7) & 0xFFu) >= 0x90u) ? 1u : 0u;
  }
  return __any((int)bad) != 0;
}

// ---------------- Kernel 1: weight transpose -> WT[g][n][kcat] (bf16) ----
// grid 8192 x 256. m8 = bid>>10 = 2*g + phase (0=x,1=h). 64x64 tiles.
template <bool F32>
__global__ __launch_bounds__(256) void wt_transpose_kernel(
    const void* __restrict__ w0, const void* __restrict__ w1,
    const void* __restrict__ w2, const void* __restrict__ w3,
    const void* __restrict__ w4, const void* __restrict__ w5,
    const void* __restrict__ w6, const void* __restrict__ w7,
    u16* __restrict__ WT, const u16* __restrict__ Xu) {
  if (input_is_f32(Xu) != F32) return;
  __shared__ u16 tile[64][65];
  const int bid = blockIdx.x;
  const int m8 = bid >> 10;
  const void* srcs[8] = {w0, w1, w2, w3, w4, w5, w6, w7};
  const int g = m8 >> 1, ph = m8 & 1;
  const int tt = bid & 1023;
  const int k0 = (tt >> 5) << 6;
  const int n0 = (tt & 31) << 6;
  const int t = threadIdx.x;

#pragma unroll
  for (int i = 0; i < 4; ++i) {
    const int q = t + (i << 8);
    const int row = q >> 4;        // k within tile
    const int cx = (q & 15) << 2;  // n within tile (4 elems)
    if (F32) {
      const float* src = (const float*)srcs[m8];
      f32x4 v = *(const f32x4*)(src + (size_t)(k0 + row) * 2048 + n0 + cx);
      tile[row][cx + 0] = f2b(v[0]);
      tile[row][cx + 1] = f2b(v[1]);
      tile[row][cx + 2] = f2b(v[2]);
      tile[row][cx + 3] = f2b(v[3]);
    } else {
      const u16* src = (const u16*)srcs[m8];
      u16x4 v = *(const u16x4*)(src + (size_t)(k0 + row) * 2048 + n0 + cx);
      tile[row][cx + 0] = v[0];
      tile[row][cx + 1] = v[1];
      tile[row][cx + 2] = v[2];
      tile[row][cx + 3] = v[3];
    }
  }
  __syncthreads();
  const size_t gbase = ((size_t)g << 23) + (size_t)ph * 2048 + k0;
#pragma unroll
  for (int i = 0; i < 4; ++i) {
    const int q = t + (i << 8);
    const int nrow = q >> 4;       // n within tile
    const int kx = (q & 15) << 2;  // k within tile (4 elems)
    u16x4 v;
    v[0] = tile[kx + 0][nrow];
    v[1] = tile[kx + 1][nrow];
    v[2] = tile[kx + 2][nrow];
    v[3] = tile[kx + 3][nrow];
    *(u16x4*)(WT + gbase + (size_t)(n0 + nrow) * 4096 + kx) = v;
  }
}

// ---------------- Kernel 2: fused GEMM + LSTM (fp32 out) ----------------
// grid 2048 = 32 m-tiles x 64 n-tiles; 256 thr = 4 waves (2 m x 2 n halves).
// 2-phase double-buffered pipeline: stage(next) || compute(cur), 1 barrier/kt.
template <bool F32>
__global__ __launch_bounds__(256, 4) void lstm_gemm_kernel(
    const void* __restrict__ Xp, const void* __restrict__ Hp,
    const void* __restrict__ Cp, const u16* __restrict__ WT,
    const void* __restrict__ bip, const void* __restrict__ bfp,
    const void* __restrict__ bop, const void* __restrict__ bcp,
    float* __restrict__ Out) {
  if (input_is_f32((const u16*)Xp) != F32) return;
  __shared__ u16 As[2][128 * 32];     // [buf][m][k]
  __shared__ u16 Bs[2][4 * 32 * 32];  // [buf][gate][n][k]

  const int t = threadIdx.x;
  const int wave = t >> 6;
  const int lane = t & 63;
  const int ln = lane & 15;
  const int quad = lane >> 4;
  const int wm = wave >> 1;
  const int wn = wave & 1;
  // XCD-aware bijective swizzle: grid 2048, 8 XCDs -> 256-block chunks.
  const int b0 = blockIdx.x;
  const int bid = ((b0 & 7) << 8) + (b0 >> 3);
  const int m0 = (bid >> 6) << 7;
  const int n0 = (bid & 63) << 5;

  // Per-thread staging addresses (strength-reduced; kt adds kt*32 u16).
  const int ko_l = (t & 3) << 3;              // k-offset within 32 (x8 u16)
  const int arow = m0 + (t >> 2);             // i=0 A row; i=1 adds 64
  const u16* aX = (const u16*)Xp + (size_t)arow * 2048 + ko_l;
  const u16* aH = (const u16*)Hp + (size_t)arow * 2048 + ko_l;
  const u16* bW = WT + (((size_t)(t >> 7)) << 23) +
                  (size_t)(n0 + ((t & 127) >> 2)) * 4096 + ko_l;

  f32x4 acc[4][4];
#pragma unroll
  for (int g = 0; g < 4; ++g)
#pragma unroll
    for (int im = 0; im < 4; ++im) acc[g][im] = (f32x4)0.0f;

  // ---- staging (issue loads for tile ktg into buffer buf) ----
  auto stage = [&](int buf, int ktg) {
    const int kk = (ktg & 63) << 5;
    if (!F32) {
      const u16* a = (ktg < 64 ? aX : aH) + kk;
      u16* da = &As[buf][t * 8];
      gload_lds16(a, da);
      gload_lds16(a + 64 * 2048, da + 2048);
    } else {
      const float* abase = (ktg < 64 ? (const float*)Xp : (const float*)Hp) +
                           (size_t)arow * 2048 + ko_l + kk;
      u16* da = &As[buf][t * 8];
#pragma unroll
      for (int i = 0; i < 2; ++i) {
        const float* p = abase + (size_t)i * 64 * 2048;
        f32x4 v0 = *(const f32x4*)p;
        f32x4 v1 = *(const f32x4*)(p + 4);
        u16x8 w;
        w[0] = f2b(v0[0]); w[1] = f2b(v0[1]); w[2] = f2b(v0[2]); w[3] = f2b(v0[3]);
        w[4] = f2b(v1[0]); w[5] = f2b(v1[1]); w[6] = f2b(v1[2]); w[7] = f2b(v1[3]);
        *(u16x8*)(da + i * 2048) = w;
      }
    }
    const u16* b = bW + ((size_t)ktg << 5);
    u16* db = &Bs[buf][t * 8];
    gload_lds16(b, db);
    gload_lds16(b + (1 << 24), db + 2048);  // c=t+256 -> gate += 2
  };

  // ---- compute (ds_read fragments from buffer buf, 16 MFMA) ----
  auto compute = [&](int buf) {
    const bf16x8* As8 = (const bf16x8*)&As[buf][0];
    const bf16x8* Bs8 = (const bf16x8*)&Bs[buf][0];
    bf16x8 a[4], b[4];
#pragma unroll
    for (int im = 0; im < 4; ++im)
      a[im] = As8[(wm * 64 + im * 16 + ln) * 4 + quad];
#pragma unroll
    for (int g = 0; g < 4; ++g)
      b[g] = Bs8[(g * 32 + wn * 16 + ln) * 4 + quad];
#pragma unroll
    for (int g = 0; g < 4; ++g)
#pragma unroll
      for (int im = 0; im < 4; ++im)
        acc[g][im] = __builtin_amdgcn_mfma_f32_16x16x32_bf16(a[im], b[g],
                                                             acc[g][im], 0, 0, 0);
  };

  // ---- 2-phase pipeline: prologue + unrolled x2 main loop ----
  stage(0, 0);
  __syncthreads();  // compiler drains vmcnt(0)/lgkmcnt(0): tile 0 ready
  for (int ktg = 0; ktg < 128; ktg += 2) {
    stage(1, ktg + 1);   // issue next-tile loads (async, other buffer)
    compute(0);          // consume current tile into registers
    __syncthreads();     // drain: tile ktg+1 ready; all waves done with buf0
    if (ktg + 2 < 128) stage(0, ktg + 2);
    compute(1);
    __syncthreads();
  }

  // Epilogue: bias + activations + elementwise; FP32 stores.
  const int ncol = n0 + wn * 16 + ln;
  float Bi, Bf, Bo, Bc;
  if (F32) {
    Bi = ((const float*)bip)[ncol]; Bf = ((const float*)bfp)[ncol];
    Bo = ((const float*)bop)[ncol]; Bc = ((const float*)bcp)[ncol];
  } else {
    Bi = b2f(((const u16*)bip)[ncol]); Bf = b2f(((const u16*)bfp)[ncol]);
    Bo = b2f(((const u16*)bop)[ncol]); Bc = b2f(((const u16*)bcp)[ncol]);
  }
#pragma unroll
  for (int im = 0; im < 4; ++im) {
#pragma unroll
    for (int r = 0; r < 4; ++r) {
      const int m = m0 + wm * 64 + im * 16 + quad * 4 + r;
      const size_t idx = (size_t)m * 2048 + ncol;
      const float gi = sigmoidf_(acc[0][im][r] + Bi);
      const float gf = sigmoidf_(acc[1][im][r] + Bf);
      const float go = sigmoidf_(acc[2][im][r] + Bo);
      const float gc = tanh_fast(acc[3][im][r] + Bc);
      const float c_in = F32 ? ((const float*)Cp)[idx] : b2f(((const u16*)Cp)[idx]);
      const float ct = gf * c_in + gi * gc;
      const float ht = go * tanh_fast(ct);
      Out[idx] = ht;             // h_t (fp32)
      Out[idx + BH_TOTAL] = ct;  // c_t (fp32)
    }
  }
}

extern "C" void kernel_launch(void* const* d_in, const int* in_sizes, int n_in,
                              void* d_out, int out_size, void* d_ws,
                              size_t ws_size, hipStream_t stream) {
  const u16* Xu = (const u16*)d_in[0];
  u16* WT = (u16*)d_ws;  // 64 MiB

  hipLaunchKernelGGL((wt_transpose_kernel<false>), dim3(8192), dim3(256), 0,
                     stream, d_in[3], d_in[4], d_in[5], d_in[6], d_in[7],
                     d_in[8], d_in[9], d_in[10], WT, Xu);
  hipLaunchKernelGGL((wt_transpose_kernel<true>), dim3(8192), dim3(256), 0,
                     stream, d_in[3], d_in[4], d_in[5], d_in[6], d_in[7],
                     d_in[8], d_in[9], d_in[10], WT, Xu);
  hipLaunchKernelGGL((lstm_gemm_kernel<false>), dim3(2048), dim3(256), 0,
                     stream, d_in[0], d_in[1], d_in[2], WT, d_in[11], d_in[12],
                     d_in[13], d_in[14], (float*)d_out);
  hipLaunchKernelGGL((lstm_gemm_kernel<true>), dim3(2048), dim3(256), 0,
                     stream, d_in[0], d_in[1], d_in[2], WT, d_in[11], d_in[12],
                     d_in[13], d_in[14], (float*)d_out);
}

// Round 7
// 652.406 us; speedup vs baseline: 1.1888x; 1.0652x over previous
//
#include <hip/hip_runtime.h>
#include <hip/hip_bf16.h>

// SlowLSTM on MI355X (gfx950). B=4096, D=H=2048.
// Round 10: round-9 measured gemm 484us, MfmaUtil 25 / VALU 31. Forensics:
// in_npz 216MB => harness inputs are FP32, so the LIVE variant is <true>,
// whose A-staging was still reg+f2b+ds_write (serial load->cvt->write chain
// in the K-loop; the round-4 DMA-A only covered the bf16 path). Fix: convert
// X,H fp32->bf16 ONCE (kernel 0, ws +32MiB, guarded by ws_size>=96MiB with
// reg-staging fallback), then GEMM stages A via global_load_lds uniformly.
// Pipeline (2-buffer stage-ahead, 1 barrier/kt, verified round 9) unchanged.
// SQ_LDS_BANK_CONFLICT pegged at 2^25 in all dispatches = saturated counter;
// bank-audit of fragment reads shows even 32-bank tiling (8-cyc b128 floor).

typedef unsigned short u16;
typedef __attribute__((ext_vector_type(4))) unsigned short u16x4;
typedef __attribute__((ext_vector_type(8))) unsigned short u16x8;
typedef __attribute__((ext_vector_type(8))) __bf16 bf16x8;
typedef __attribute__((ext_vector_type(4))) float f32x4;

#define BH_TOTAL (4096 * 2048)

__device__ __forceinline__ float b2f(u16 u) {
  union { unsigned int i; float f; } v; v.i = ((unsigned int)u) << 16; return v.f;
}
__device__ __forceinline__ u16 f2b(float f) {
  union { float f; unsigned int i; } v; v.f = f;
  unsigned int r = v.i + 0x7fffu + ((v.i >> 16) & 1u);  // RNE
  return (u16)(r >> 16);
}
__device__ __forceinline__ float sigmoidf_(float x) {
  return 1.0f / (1.0f + __expf(-x));
}
// tanh(x) = 1 - 2/(e^{2x}+1); exact at +-inf via __expf saturation.
__device__ __forceinline__ float tanh_fast(float x) {
  float e = __expf(2.0f * x);
  return 1.0f - 2.0f / (e + 1.0f);
}

// Async global->LDS, 16 bytes per lane. LDS dest must be linear in lane order
// (wave-uniform base + lane*16) -- our t*8 u16 mapping satisfies this.
__device__ __forceinline__ void gload_lds16(const u16* g, u16* l) {
  __builtin_amdgcn_global_load_lds(
      (const __attribute__((address_space(1))) unsigned int*)g,
      (__attribute__((address_space(3))) unsigned int*)l, 16, 0, 0);
}

// fp32 read as u16 shows mantissa halves with huge "bf16 exponents";
// N(0,1)-scale bf16 never has exponent >= 0x90 (|v| >= 2^17).
__device__ __forceinline__ bool input_is_f32(const u16* Xu) {
  const int lane = threadIdx.x & 63;
  unsigned bad = 0;
#pragma unroll
  for (int j = 0; j < 4; ++j) {
    unsigned u = Xu[lane + (j << 6)];
    bad |= (((u >> 7) & 0xFFu) >= 0x90u) ? 1u : 0u;
  }
  return __any((int)bad) != 0;
}

// ---------------- Kernel 0: X,H fp32 -> bf16 into workspace ------------
// grid 4096 x 256; each thread converts 8 floats of X and 8 of H.
__global__ __launch_bounds__(256) void conv_f32_bf16_kernel(
    const float* __restrict__ X, const float* __restrict__ H,
    u16* __restrict__ Xb, u16* __restrict__ Hb, const u16* __restrict__ Xu) {
  if (!input_is_f32(Xu)) return;
  const size_t base = ((size_t)blockIdx.x * 256 + threadIdx.x) * 8;
#pragma unroll
  for (int s = 0; s < 2; ++s) {
    const float* src = s ? H : X;
    u16* dst = s ? Hb : Xb;
    f32x4 v0 = *(const f32x4*)(src + base);
    f32x4 v1 = *(const f32x4*)(src + base + 4);
    u16x8 w;
    w[0] = f2b(v0[0]); w[1] = f2b(v0[1]); w[2] = f2b(v0[2]); w[3] = f2b(v0[3]);
    w[4] = f2b(v1[0]); w[5] = f2b(v1[1]); w[6] = f2b(v1[2]); w[7] = f2b(v1[3]);
    *(u16x8*)(dst + base) = w;
  }
}

// ---------------- Kernel 1: weight transpose -> WT[g][n][kcat] (bf16) ----
// grid 8192 x 256. m8 = bid>>10 = 2*g + phase (0=x,1=h). 64x64 tiles.
template <bool F32>
__global__ __launch_bounds__(256) void wt_transpose_kernel(
    const void* __restrict__ w0, const void* __restrict__ w1,
    const void* __restrict__ w2, const void* __restrict__ w3,
    const void* __restrict__ w4, const void* __restrict__ w5,
    const void* __restrict__ w6, const void* __restrict__ w7,
    u16* __restrict__ WT, const u16* __restrict__ Xu) {
  if (input_is_f32(Xu) != F32) return;
  __shared__ u16 tile[64][65];
  const int bid = blockIdx.x;
  const int m8 = bid >> 10;
  const void* srcs[8] = {w0, w1, w2, w3, w4, w5, w6, w7};
  const int g = m8 >> 1, ph = m8 & 1;
  const int tt = bid & 1023;
  const int k0 = (tt >> 5) << 6;
  const int n0 = (tt & 31) << 6;
  const int t = threadIdx.x;

#pragma unroll
  for (int i = 0; i < 4; ++i) {
    const int q = t + (i << 8);
    const int row = q >> 4;        // k within tile
    const int cx = (q & 15) << 2;  // n within tile (4 elems)
    if (F32) {
      const float* src = (const float*)srcs[m8];
      f32x4 v = *(const f32x4*)(src + (size_t)(k0 + row) * 2048 + n0 + cx);
      tile[row][cx + 0] = f2b(v[0]);
      tile[row][cx + 1] = f2b(v[1]);
      tile[row][cx + 2] = f2b(v[2]);
      tile[row][cx + 3] = f2b(v[3]);
    } else {
      const u16* src = (const u16*)srcs[m8];
      u16x4 v = *(const u16x4*)(src + (size_t)(k0 + row) * 2048 + n0 + cx);
      tile[row][cx + 0] = v[0];
      tile[row][cx + 1] = v[1];
      tile[row][cx + 2] = v[2];
      tile[row][cx + 3] = v[3];
    }
  }
  __syncthreads();
  const size_t gbase = ((size_t)g << 23) + (size_t)ph * 2048 + k0;
#pragma unroll
  for (int i = 0; i < 4; ++i) {
    const int q = t + (i << 8);
    const int nrow = q >> 4;       // n within tile
    const int kx = (q & 15) << 2;  // k within tile (4 elems)
    u16x4 v;
    v[0] = tile[kx + 0][nrow];
    v[1] = tile[kx + 1][nrow];
    v[2] = tile[kx + 2][nrow];
    v[3] = tile[kx + 3][nrow];
    *(u16x4*)(WT + gbase + (size_t)(n0 + nrow) * 4096 + kx) = v;
  }
}

// ---------------- Kernel 2: fused GEMM + LSTM (fp32 out) ----------------
// grid 2048 = 32 m-tiles x 64 n-tiles; 256 thr = 4 waves (2 m x 2 n halves).
// 2-phase double-buffered pipeline: stage(next) || compute(cur), 1 barrier/kt.
// F32: C/bias dtype is fp32. ADMA: A sources are bf16, staged via DMA.
template <bool F32, bool ADMA>
__global__ __launch_bounds__(256, 4) void lstm_gemm_kernel(
    const u16* __restrict__ Xguard, const void* __restrict__ AxP,
    const void* __restrict__ AhP, const void* __restrict__ Cp,
    const u16* __restrict__ WT, const void* __restrict__ bip,
    const void* __restrict__ bfp, const void* __restrict__ bop,
    const void* __restrict__ bcp, float* __restrict__ Out) {
  if (input_is_f32(Xguard) != F32) return;
  __shared__ u16 As[2][128 * 32];     // [buf][m][k]
  __shared__ u16 Bs[2][4 * 32 * 32];  // [buf][gate][n][k]

  const int t = threadIdx.x;
  const int wave = t >> 6;
  const int lane = t & 63;
  const int ln = lane & 15;
  const int quad = lane >> 4;
  const int wm = wave >> 1;
  const int wn = wave & 1;
  // XCD-aware bijective swizzle: grid 2048, 8 XCDs -> 256-block chunks.
  const int b0 = blockIdx.x;
  const int bid = ((b0 & 7) << 8) + (b0 >> 3);
  const int m0 = (bid >> 6) << 7;
  const int n0 = (bid & 63) << 5;

  // Per-thread staging addresses (strength-reduced; kt adds kt*32 u16).
  const int ko_l = (t & 3) << 3;              // k-offset within 32 (x8 u16)
  const int arow = m0 + (t >> 2);             // i=0 A row; i=1 adds 64
  const u16* aX = (const u16*)AxP + (size_t)arow * 2048 + ko_l;
  const u16* aH = (const u16*)AhP + (size_t)arow * 2048 + ko_l;
  const u16* bW = WT + (((size_t)(t >> 7)) << 23) +
                  (size_t)(n0 + ((t & 127) >> 2)) * 4096 + ko_l;

  f32x4 acc[4][4];
#pragma unroll
  for (int g = 0; g < 4; ++g)
#pragma unroll
    for (int im = 0; im < 4; ++im) acc[g][im] = (f32x4)0.0f;

  // ---- staging (issue loads for tile ktg into buffer buf) ----
  auto stage = [&](int buf, int ktg) {
    const int kk = (ktg & 63) << 5;
    u16* da = &As[buf][t * 8];
    if (ADMA) {
      const u16* a = (ktg < 64 ? aX : aH) + kk;
      gload_lds16(a, da);
      gload_lds16(a + 64 * 2048, da + 2048);
    } else {
      const float* abase = (ktg < 64 ? (const float*)AxP : (const float*)AhP) +
                           (size_t)arow * 2048 + ko_l + kk;
#pragma unroll
      for (int i = 0; i < 2; ++i) {
        const float* p = abase + (size_t)i * 64 * 2048;
        f32x4 v0 = *(const f32x4*)p;
        f32x4 v1 = *(const f32x4*)(p + 4);
        u16x8 w;
        w[0] = f2b(v0[0]); w[1] = f2b(v0[1]); w[2] = f2b(v0[2]); w[3] = f2b(v0[3]);
        w[4] = f2b(v1[0]); w[5] = f2b(v1[1]); w[6] = f2b(v1[2]); w[7] = f2b(v1[3]);
        *(u16x8*)(da + i * 2048) = w;
      }
    }
    const u16* b = bW + ((size_t)ktg << 5);
    u16* db = &Bs[buf][t * 8];
    gload_lds16(b, db);
    gload_lds16(b + (1 << 24), db + 2048);  // c=t+256 -> gate += 2
  };

  // ---- compute (ds_read fragments from buffer buf, 16 MFMA) ----
  auto compute = [&](int buf) {
    const bf16x8* As8 = (const bf16x8*)&As[buf][0];
    const bf16x8* Bs8 = (const bf16x8*)&Bs[buf][0];
    bf16x8 a[4], b[4];
#pragma unroll
    for (int im = 0; im < 4; ++im)
      a[im] = As8[(wm * 64 + im * 16 + ln) * 4 + quad];
#pragma unroll
    for (int g = 0; g < 4; ++g)
      b[g] = Bs8[(g * 32 + wn * 16 + ln) * 4 + quad];
#pragma unroll
    for (int g = 0; g < 4; ++g)
#pragma unroll
      for (int im = 0; im < 4; ++im)
        acc[g][im] = __builtin_amdgcn_mfma_f32_16x16x32_bf16(a[im], b[g],
                                                             acc[g][im], 0, 0, 0);
  };

  // ---- 2-phase pipeline: prologue + unrolled x2 main loop ----
  stage(0, 0);
  __syncthreads();  // compiler drains vmcnt(0)/lgkmcnt(0): tile 0 ready
  for (int ktg = 0; ktg < 128; ktg += 2) {
    stage(1, ktg + 1);   // issue next-tile loads (async, other buffer)
    compute(0);          // consume current tile into registers
    __syncthreads();     // drain: tile ktg+1 ready; all waves done with buf0
    if (ktg + 2 < 128) stage(0, ktg + 2);
    compute(1);
    __syncthreads();
  }

  // Epilogue: bias + activations + elementwise; FP32 stores.
  const int ncol = n0 + wn * 16 + ln;
  float Bi, Bf, Bo, Bc;
  if (F32) {
    Bi = ((const float*)bip)[ncol]; Bf = ((const float*)bfp)[ncol];
    Bo = ((const float*)bop)[ncol]; Bc = ((const float*)bcp)[ncol];
  } else {
    Bi = b2f(((const u16*)bip)[ncol]); Bf = b2f(((const u16*)bfp)[ncol]);
    Bo = b2f(((const u16*)bop)[ncol]); Bc = b2f(((const u16*)bcp)[ncol]);
  }
#pragma unroll
  for (int im = 0; im < 4; ++im) {
#pragma unroll
    for (int r = 0; r < 4; ++r) {
      const int m = m0 + wm * 64 + im * 16 + quad * 4 + r;
      const size_t idx = (size_t)m * 2048 + ncol;
      const float gi = sigmoidf_(acc[0][im][r] + Bi);
      const float gf = sigmoidf_(acc[1][im][r] + Bf);
      const float go = sigmoidf_(acc[2][im][r] + Bo);
      const float gc = tanh_fast(acc[3][im][r] + Bc);
      const float c_in = F32 ? ((const float*)Cp)[idx] : b2f(((const u16*)Cp)[idx]);
      const float ct = gf * c_in + gi * gc;
      const float ht = go * tanh_fast(ct);
      Out[idx] = ht;             // h_t (fp32)
      Out[idx + BH_TOTAL] = ct;  // c_t (fp32)
    }
  }
}

extern "C" void kernel_launch(void* const* d_in, const int* in_sizes, int n_in,
                              void* d_out, int out_size, void* d_ws,
                              size_t ws_size, hipStream_t stream) {
  const u16* Xu = (const u16*)d_in[0];
  u16* WT = (u16*)d_ws;            // 64 MiB: WT[4][2048][4096] bf16
  u16* Xb = WT + 33554432;         // +64 MiB: X as bf16 (16 MiB)
  u16* Hb = Xb + 8388608;          // +80 MiB: H as bf16 (16 MiB)
  const bool big_ws = ws_size >= (size_t)96 * 1024 * 1024;

  hipLaunchKernelGGL((wt_transpose_kernel<false>), dim3(8192), dim3(256), 0,
                     stream, d_in[3], d_in[4], d_in[5], d_in[6], d_in[7],
                     d_in[8], d_in[9], d_in[10], WT, Xu);
  hipLaunchKernelGGL((wt_transpose_kernel<true>), dim3(8192), dim3(256), 0,
                     stream, d_in[3], d_in[4], d_in[5], d_in[6], d_in[7],
                     d_in[8], d_in[9], d_in[10], WT, Xu);
  if (big_ws) {
    hipLaunchKernelGGL(conv_f32_bf16_kernel, dim3(4096), dim3(256), 0, stream,
                       (const float*)d_in[0], (const float*)d_in[1], Xb, Hb,
                       Xu);
  }
  // bf16 inputs: A staged directly from inputs via DMA.
  hipLaunchKernelGGL((lstm_gemm_kernel<false, true>), dim3(2048), dim3(256), 0,
                     stream, Xu, d_in[0], d_in[1], d_in[2], WT, d_in[11],
                     d_in[12], d_in[13], d_in[14], (float*)d_out);
  // fp32 inputs: A staged from pre-converted bf16 (big ws) or reg-staged.
  if (big_ws) {
    hipLaunchKernelGGL((lstm_gemm_kernel<true, true>), dim3(2048), dim3(256),
                       0, stream, Xu, Xb, Hb, d_in[2], WT, d_in[11], d_in[12],
                       d_in[13], d_in[14], (float*)d_out);
  } else {
    hipLaunchKernelGGL((lstm_gemm_kernel<true, false>), dim3(2048), dim3(256),
                       0, stream, Xu, d_in[0], d_in[1], d_in[2], WT, d_in[11],
                       d_in[12], d_in[13], d_in[14], (float*)d_out);
  }
}

// Round 8
// 622.369 us; speedup vs baseline: 1.2461x; 1.0483x over previous
//
#include <hip/hip_runtime.h>
#include <hip/hip_bf16.h>

// SlowLSTM on MI355X (gfx950). B=4096, D=H=2048.
// Round 11: round-10 measured gemm 408us, MfmaUtil 29.7 / VALU 18.2 (f2b
// elimination confirmed). Residual: 961 cyc/block-kt vs ~300 compute =>
// still latency-bound; __syncthreads' vmcnt(0) drain collapses the double
// buffer (next tile's DMAs forced complete too). Fix = T4 counted vmcnt:
// 3-buffer LDS (48KB), depth-2 lookahead, raw s_barrier + per-wave
// "s_waitcnt vmcnt(4) lgkmcnt(0)" (never 0 in loop; m218 +38-73%).
// Safety: own-reads drained before barrier; overwriting stage issued after.
// Also: host-side dtype dispatch via in_sizes[0] (bytes) removes dead
// variant launches; device guards kept as backstop.

typedef unsigned short u16;
typedef __attribute__((ext_vector_type(4))) unsigned short u16x4;
typedef __attribute__((ext_vector_type(8))) unsigned short u16x8;
typedef __attribute__((ext_vector_type(8))) __bf16 bf16x8;
typedef __attribute__((ext_vector_type(4))) float f32x4;

#define BH_TOTAL (4096 * 2048)

__device__ __forceinline__ float b2f(u16 u) {
  union { unsigned int i; float f; } v; v.i = ((unsigned int)u) << 16; return v.f;
}
__device__ __forceinline__ u16 f2b(float f) {
  union { float f; unsigned int i; } v; v.f = f;
  unsigned int r = v.i + 0x7fffu + ((v.i >> 16) & 1u);  // RNE
  return (u16)(r >> 16);
}
__device__ __forceinline__ float sigmoidf_(float x) {
  return 1.0f / (1.0f + __expf(-x));
}
// tanh(x) = 1 - 2/(e^{2x}+1); exact at +-inf via __expf saturation.
__device__ __forceinline__ float tanh_fast(float x) {
  float e = __expf(2.0f * x);
  return 1.0f - 2.0f / (e + 1.0f);
}

// Async global->LDS, 16 bytes per lane. LDS dest must be linear in lane order
// (wave-uniform base + lane*16) -- our t*8 u16 mapping satisfies this.
__device__ __forceinline__ void gload_lds16(const u16* g, u16* l) {
  __builtin_amdgcn_global_load_lds(
      (const __attribute__((address_space(1))) unsigned int*)g,
      (__attribute__((address_space(3))) unsigned int*)l, 16, 0, 0);
}

// fp32 read as u16 shows mantissa halves with huge "bf16 exponents";
// N(0,1)-scale bf16 never has exponent >= 0x90 (|v| >= 2^17).
__device__ __forceinline__ bool input_is_f32(const u16* Xu) {
  const int lane = threadIdx.x & 63;
  unsigned bad = 0;
#pragma unroll
  for (int j = 0; j < 4; ++j) {
    unsigned u = Xu[lane + (j << 6)];
    bad |= (((u >> 7) & 0xFFu) >= 0x90u) ? 1u : 0u;
  }
  return __any((int)bad) != 0;
}

// ---------------- Kernel 0: X,H fp32 -> bf16 into workspace ------------
// grid 4096 x 256; each thread converts 8 floats of X and 8 of H.
__global__ __launch_bounds__(256) void conv_f32_bf16_kernel(
    const float* __restrict__ X, const float* __restrict__ H,
    u16* __restrict__ Xb, u16* __restrict__ Hb, const u16* __restrict__ Xu) {
  if (!input_is_f32(Xu)) return;
  const size_t base = ((size_t)blockIdx.x * 256 + threadIdx.x) * 8;
#pragma unroll
  for (int s = 0; s < 2; ++s) {
    const float* src = s ? H : X;
    u16* dst = s ? Hb : Xb;
    f32x4 v0 = *(const f32x4*)(src + base);
    f32x4 v1 = *(const f32x4*)(src + base + 4);
    u16x8 w;
    w[0] = f2b(v0[0]); w[1] = f2b(v0[1]); w[2] = f2b(v0[2]); w[3] = f2b(v0[3]);
    w[4] = f2b(v1[0]); w[5] = f2b(v1[1]); w[6] = f2b(v1[2]); w[7] = f2b(v1[3]);
    *(u16x8*)(dst + base) = w;
  }
}

// ---------------- Kernel 1: weight transpose -> WT[g][n][kcat] (bf16) ----
// grid 8192 x 256. m8 = bid>>10 = 2*g + phase (0=x,1=h). 64x64 tiles.
template <bool F32>
__global__ __launch_bounds__(256) void wt_transpose_kernel(
    const void* __restrict__ w0, const void* __restrict__ w1,
    const void* __restrict__ w2, const void* __restrict__ w3,
    const void* __restrict__ w4, const void* __restrict__ w5,
    const void* __restrict__ w6, const void* __restrict__ w7,
    u16* __restrict__ WT, const u16* __restrict__ Xu) {
  if (input_is_f32(Xu) != F32) return;
  __shared__ u16 tile[64][65];
  const int bid = blockIdx.x;
  const int m8 = bid >> 10;
  const void* srcs[8] = {w0, w1, w2, w3, w4, w5, w6, w7};
  const int g = m8 >> 1, ph = m8 & 1;
  const int tt = bid & 1023;
  const int k0 = (tt >> 5) << 6;
  const int n0 = (tt & 31) << 6;
  const int t = threadIdx.x;

#pragma unroll
  for (int i = 0; i < 4; ++i) {
    const int q = t + (i << 8);
    const int row = q >> 4;        // k within tile
    const int cx = (q & 15) << 2;  // n within tile (4 elems)
    if (F32) {
      const float* src = (const float*)srcs[m8];
      f32x4 v = *(const f32x4*)(src + (size_t)(k0 + row) * 2048 + n0 + cx);
      tile[row][cx + 0] = f2b(v[0]);
      tile[row][cx + 1] = f2b(v[1]);
      tile[row][cx + 2] = f2b(v[2]);
      tile[row][cx + 3] = f2b(v[3]);
    } else {
      const u16* src = (const u16*)srcs[m8];
      u16x4 v = *(const u16x4*)(src + (size_t)(k0 + row) * 2048 + n0 + cx);
      tile[row][cx + 0] = v[0];
      tile[row][cx + 1] = v[1];
      tile[row][cx + 2] = v[2];
      tile[row][cx + 3] = v[3];
    }
  }
  __syncthreads();
  const size_t gbase = ((size_t)g << 23) + (size_t)ph * 2048 + k0;
#pragma unroll
  for (int i = 0; i < 4; ++i) {
    const int q = t + (i << 8);
    const int nrow = q >> 4;       // n within tile
    const int kx = (q & 15) << 2;  // k within tile (4 elems)
    u16x4 v;
    v[0] = tile[kx + 0][nrow];
    v[1] = tile[kx + 1][nrow];
    v[2] = tile[kx + 2][nrow];
    v[3] = tile[kx + 3][nrow];
    *(u16x4*)(WT + gbase + (size_t)(n0 + nrow) * 4096 + kx) = v;
  }
}

// ---------------- Kernel 2: fused GEMM + LSTM (fp32 out) ----------------
// grid 2048 = 32 m-tiles x 64 n-tiles; 256 thr = 4 waves (2 m x 2 n halves).
// 3-buffer depth-2 pipeline, raw s_barrier + counted vmcnt (T4).
template <bool F32, bool ADMA>
__global__ __launch_bounds__(256, 3) void lstm_gemm_kernel(
    const u16* __restrict__ Xguard, const void* __restrict__ AxP,
    const void* __restrict__ AhP, const void* __restrict__ Cp,
    const u16* __restrict__ WT, const void* __restrict__ bip,
    const void* __restrict__ bfp, const void* __restrict__ bop,
    const void* __restrict__ bcp, float* __restrict__ Out) {
  if (input_is_f32(Xguard) != F32) return;
  __shared__ u16 As[3][128 * 32];     // [buf][m][k]   3 x 8 KiB
  __shared__ u16 Bs[3][4 * 32 * 32];  // [buf][g][n][k] 3 x 8 KiB

  const int t = threadIdx.x;
  const int wave = t >> 6;
  const int lane = t & 63;
  const int ln = lane & 15;
  const int quad = lane >> 4;
  const int wm = wave >> 1;
  const int wn = wave & 1;
  // XCD-aware bijective swizzle: grid 2048, 8 XCDs -> 256-block chunks.
  const int b0 = blockIdx.x;
  const int bid = ((b0 & 7) << 8) + (b0 >> 3);
  const int m0 = (bid >> 6) << 7;
  const int n0 = (bid & 63) << 5;

  // Per-thread staging addresses (kt adds kt*32 u16).
  const int ko_l = (t & 3) << 3;              // k-offset within 32 (x8 u16)
  const int arow = m0 + (t >> 2);             // i=0 A row; i=1 adds 64
  const u16* aX = (const u16*)AxP + (size_t)arow * 2048 + ko_l;
  const u16* aH = (const u16*)AhP + (size_t)arow * 2048 + ko_l;
  const u16* bW = WT + (((size_t)(t >> 7)) << 23) +
                  (size_t)(n0 + ((t & 127) >> 2)) * 4096 + ko_l;

  f32x4 acc[4][4];
#pragma unroll
  for (int g = 0; g < 4; ++g)
#pragma unroll
    for (int im = 0; im < 4; ++im) acc[g][im] = (f32x4)0.0f;

  // ---- staging: issue loads for tile ktg into buffer buf ----
  // ADMA path: 4 vmem ops/thread (2 A-DMA + 2 B-DMA), all async to LDS.
  // reg path: A via f32 loads (self-drained) + cvt + ds_write; 2 B-DMA.
  auto stage = [&](int buf, int ktg) {
    const int kk = (ktg & 63) << 5;
    u16* da = &As[buf][t * 8];
    if (ADMA) {
      const u16* a = (ktg < 64 ? aX : aH) + kk;
      gload_lds16(a, da);
      gload_lds16(a + 64 * 2048, da + 2048);
    } else {
      const float* abase = (ktg < 64 ? (const float*)AxP : (const float*)AhP) +
                           (size_t)arow * 2048 + ko_l + kk;
#pragma unroll
      for (int i = 0; i < 2; ++i) {
        const float* p = abase + (size_t)i * 64 * 2048;
        f32x4 v0 = *(const f32x4*)p;
        f32x4 v1 = *(const f32x4*)(p + 4);
        u16x8 w;
        w[0] = f2b(v0[0]); w[1] = f2b(v0[1]); w[2] = f2b(v0[2]); w[3] = f2b(v0[3]);
        w[4] = f2b(v1[0]); w[5] = f2b(v1[1]); w[6] = f2b(v1[2]); w[7] = f2b(v1[3]);
        *(u16x8*)(da + i * 2048) = w;
      }
    }
    const u16* b = bW + ((size_t)ktg << 5);
    u16* db = &Bs[buf][t * 8];
    gload_lds16(b, db);
    gload_lds16(b + (1 << 24), db + 2048);  // c=t+256 -> gate += 2
  };

  // ---- compute: ds_read fragments from buffer buf, 16 MFMA ----
  auto compute = [&](int buf) {
    const bf16x8* As8 = (const bf16x8*)&As[buf][0];
    const bf16x8* Bs8 = (const bf16x8*)&Bs[buf][0];
    bf16x8 a[4], b[4];
#pragma unroll
    for (int im = 0; im < 4; ++im)
      a[im] = As8[(wm * 64 + im * 16 + ln) * 4 + quad];
#pragma unroll
    for (int g = 0; g < 4; ++g)
      b[g] = Bs8[(g * 32 + wn * 16 + ln) * 4 + quad];
#pragma unroll
    for (int g = 0; g < 4; ++g)
#pragma unroll
      for (int im = 0; im < 4; ++im)
        acc[g][im] = __builtin_amdgcn_mfma_f32_16x16x32_bf16(a[im], b[g],
                                                             acc[g][im], 0, 0, 0);
  };

  // Counted wait: oldest stage resident, next stage's loads stay in flight.
  // Also drains this wave's own LDS reads (overwrite safety before barrier).
  auto wait_steady = [&]() {
    if (ADMA)
      asm volatile("s_waitcnt vmcnt(4) lgkmcnt(0)" ::: "memory");
    else
      asm volatile("s_waitcnt vmcnt(2) lgkmcnt(0)" ::: "memory");
  };

  // ---- 3-buffer depth-2 pipeline ----
  stage(0, 0);
  stage(1, 1);
#define LSTM_STEP(B, T)                  \
  wait_steady();                         \
  __builtin_amdgcn_s_barrier();          \
  asm volatile("" ::: "memory");         \
  stage(((B) + 2) % 3, (T) + 2);         \
  compute(B);

  for (int base = 0; base < 126; base += 3) {
    LSTM_STEP(0, base);
    LSTM_STEP(1, base + 1);
    LSTM_STEP(2, base + 2);
  }
#undef LSTM_STEP
  // t=126 (buf 0): stages 126,127 outstanding; steady wait completes 126.
  wait_steady();
  __builtin_amdgcn_s_barrier();
  asm volatile("" ::: "memory");
  compute(0);
  // t=127 (buf 1): final drain.
  asm volatile("s_waitcnt vmcnt(0) lgkmcnt(0)" ::: "memory");
  __builtin_amdgcn_s_barrier();
  asm volatile("" ::: "memory");
  compute(1);

  // Epilogue: bias + activations + elementwise; FP32 stores.
  const int ncol = n0 + wn * 16 + ln;
  float Bi, Bf, Bo, Bc;
  if (F32) {
    Bi = ((const float*)bip)[ncol]; Bf = ((const float*)bfp)[ncol];
    Bo = ((const float*)bop)[ncol]; Bc = ((const float*)bcp)[ncol];
  } else {
    Bi = b2f(((const u16*)bip)[ncol]); Bf = b2f(((const u16*)bfp)[ncol]);
    Bo = b2f(((const u16*)bop)[ncol]); Bc = b2f(((const u16*)bcp)[ncol]);
  }
#pragma unroll
  for (int im = 0; im < 4; ++im) {
#pragma unroll
    for (int r = 0; r < 4; ++r) {
      const int m = m0 + wm * 64 + im * 16 + quad * 4 + r;
      const size_t idx = (size_t)m * 2048 + ncol;
      const float gi = sigmoidf_(acc[0][im][r] + Bi);
      const float gf = sigmoidf_(acc[1][im][r] + Bf);
      const float go = sigmoidf_(acc[2][im][r] + Bo);
      const float gc = tanh_fast(acc[3][im][r] + Bc);
      const float c_in = F32 ? ((const float*)Cp)[idx] : b2f(((const u16*)Cp)[idx]);
      const float ct = gf * c_in + gi * gc;
      const float ht = go * tanh_fast(ct);
      Out[idx] = ht;             // h_t (fp32)
      Out[idx + BH_TOTAL] = ct;  // c_t (fp32)
    }
  }
}

extern "C" void kernel_launch(void* const* d_in, const int* in_sizes, int n_in,
                              void* d_out, int out_size, void* d_ws,
                              size_t ws_size, hipStream_t stream) {
  const u16* Xu = (const u16*)d_in[0];
  u16* WT = (u16*)d_ws;            // 64 MiB: WT[4][2048][4096] bf16
  u16* Xb = WT + 33554432;         // +64 MiB: X as bf16 (16 MiB)
  u16* Hb = Xb + 8388608;          // +80 MiB: H as bf16 (16 MiB)
  const bool big_ws = ws_size >= (size_t)96 * 1024 * 1024;

  // Host-side dtype dispatch from input byte size (device guards remain).
  const int xb = in_sizes ? in_sizes[0] : 0;
  const bool known_f32 = (xb == BH_TOTAL * 4);
  const bool known_bf16 = (xb == BH_TOTAL * 2);
  const bool do_bf16 = known_bf16 || !(known_f32 || known_bf16);
  const bool do_f32 = known_f32 || !(known_f32 || known_bf16);

  if (do_bf16) {
    hipLaunchKernelGGL((wt_transpose_kernel<false>), dim3(8192), dim3(256), 0,
                       stream, d_in[3], d_in[4], d_in[5], d_in[6], d_in[7],
                       d_in[8], d_in[9], d_in[10], WT, Xu);
    hipLaunchKernelGGL((lstm_gemm_kernel<false, true>), dim3(2048), dim3(256),
                       0, stream, Xu, d_in[0], d_in[1], d_in[2], WT, d_in[11],
                       d_in[12], d_in[13], d_in[14], (float*)d_out);
  }
  if (do_f32) {
    hipLaunchKernelGGL((wt_transpose_kernel<true>), dim3(8192), dim3(256), 0,
                       stream, d_in[3], d_in[4], d_in[5], d_in[6], d_in[7],
                       d_in[8], d_in[9], d_in[10], WT, Xu);
    if (big_ws) {
      hipLaunchKernelGGL(conv_f32_bf16_kernel, dim3(4096), dim3(256), 0,
                         stream, (const float*)d_in[0], (const float*)d_in[1],
                         Xb, Hb, Xu);
      hipLaunchKernelGGL((lstm_gemm_kernel<true, true>), dim3(2048), dim3(256),
                         0, stream, Xu, Xb, Hb, d_in[2], WT, d_in[11],
                         d_in[12], d_in[13], d_in[14], (float*)d_out);
    } else {
      hipLaunchKernelGGL((lstm_gemm_kernel<true, false>), dim3(2048),
                         dim3(256), 0, stream, Xu, d_in[0], d_in[1], d_in[2],
                         WT, d_in[11], d_in[12], d_in[13], d_in[14],
                         (float*)d_out);
    }
  }
}